// Round 1
// baseline (255.144 us; speedup 1.0000x reference)
//
#include <hip/hip_runtime.h>
#include <hip/hip_bf16.h>

// Shapes (fixed by the problem)
#define NB   16    // batch
#define NC   512   // channels
#define NSPA 1024  // h*w
#define NG   32    // groups
#define NO3  1536  // 3*C
#define GN_EPS 1e-5f
#define SCL 0.044194173824159216f  // 512^-0.5

typedef __bf16 bf16x8 __attribute__((ext_vector_type(8)));
typedef __bf16 bf16x4 __attribute__((ext_vector_type(4)));
typedef float  f32x4  __attribute__((ext_vector_type(4)));

__device__ __forceinline__ __bf16 tob(float f) { return (__bf16)f; }

// ---------------------------------------------------------------------------
// K1: GroupNorm stats -> per (b,c) affine coefs: xn = x*coefA + coefB
// grid = B*G blocks, 256 threads; each block reduces 16*1024 = 16384 floats
// ---------------------------------------------------------------------------
__global__ void gn_stats_kernel(const float* __restrict__ x,
                                const float* __restrict__ gn_scale,
                                const float* __restrict__ gn_bias,
                                float* __restrict__ coefA,
                                float* __restrict__ coefB) {
  const int bg = blockIdx.x;
  const int b = bg >> 5, g = bg & 31;
  const float4* base = (const float4*)(x + (size_t)(b * NC + g * 16) * NSPA);
  const int tid = threadIdx.x;
  float s = 0.f, ss = 0.f;
#pragma unroll
  for (int i = 0; i < 16; ++i) {
    float4 v = base[i * 256 + tid];
    s  += (v.x + v.y) + (v.z + v.w);
    ss += (v.x * v.x + v.y * v.y) + (v.z * v.z + v.w * v.w);
  }
#pragma unroll
  for (int off = 32; off; off >>= 1) {
    s  += __shfl_xor(s, off);
    ss += __shfl_xor(ss, off);
  }
  __shared__ float rs[4], rss[4];
  const int wave = tid >> 6, lane = tid & 63;
  if (lane == 0) { rs[wave] = s; rss[wave] = ss; }
  __syncthreads();
  if (tid < 16) {
    float S  = rs[0] + rs[1] + rs[2] + rs[3];
    float SS = rss[0] + rss[1] + rss[2] + rss[3];
    float mean = S * (1.f / 16384.f);
    float var  = SS * (1.f / 16384.f) - mean * mean;
    float rstd = rsqrtf(var + GN_EPS);
    int c = g * 16 + tid;
    float a = gn_scale[c] * rstd;
    coefA[b * NC + c] = a;
    coefB[b * NC + c] = gn_bias[c] - mean * a;
  }
}

// ---------------------------------------------------------------------------
// Shared MFMA inner: 64x64 tile, 4 waves in 2x2, each wave 32x32 (2x2 frags)
// LDS layout: [out-dim][k] rows of 72 bf16 (64 + 8 pad)
// ---------------------------------------------------------------------------
__device__ __forceinline__ void mfma_tile(const __bf16 (*la)[72], const __bf16 (*lb)[72],
                                          int wm, int wn, int lane, f32x4 acc[2][2]) {
  const int fr = lane & 15;
  const int fg = (lane >> 4) * 8;
#pragma unroll
  for (int ks = 0; ks < 2; ++ks) {
    bf16x8 a0 = *(const bf16x8*)&la[wm + fr][ks * 32 + fg];
    bf16x8 a1 = *(const bf16x8*)&la[wm + 16 + fr][ks * 32 + fg];
    bf16x8 b0 = *(const bf16x8*)&lb[wn + fr][ks * 32 + fg];
    bf16x8 b1 = *(const bf16x8*)&lb[wn + 16 + fr][ks * 32 + fg];
    acc[0][0] = __builtin_amdgcn_mfma_f32_16x16x32_bf16(a0, b0, acc[0][0], 0, 0, 0);
    acc[0][1] = __builtin_amdgcn_mfma_f32_16x16x32_bf16(a0, b1, acc[0][1], 0, 0, 0);
    acc[1][0] = __builtin_amdgcn_mfma_f32_16x16x32_bf16(a1, b0, acc[1][0], 0, 0, 0);
    acc[1][1] = __builtin_amdgcn_mfma_f32_16x16x32_bf16(a1, b1, acc[1][1], 0, 0, 0);
  }
}

// ---------------------------------------------------------------------------
// K2: qkv[b][o][n] = sum_c W[o][c] * (x*coefA+coefB) + bias, bf16 out
// grid (N/64=16, O3/64=24, B)
// ---------------------------------------------------------------------------
__global__ void qkv_gemm_kernel(const float* __restrict__ x,
                                const float* __restrict__ wqkv,
                                const float* __restrict__ bqkv,
                                const float* __restrict__ coefA,
                                const float* __restrict__ coefB,
                                __bf16* __restrict__ qkv) {
  const int n0 = blockIdx.x * 64;
  const int m0 = blockIdx.y * 64;
  const int b  = blockIdx.z;
  __shared__ __bf16 lA[64][72];  // [o][c]
  __shared__ __bf16 lB[64][72];  // [n][c]
  const int tid = threadIdx.x;
  const int lane = tid & 63, wave = tid >> 6;
  const int wm = (wave >> 1) * 32, wn = (wave & 1) * 32;
  f32x4 acc[2][2] = {};
  const int ar = tid >> 2, as = (tid & 3) * 16;       // A stage: row, col-seg
  const int tn4 = (tid & 15) * 4, tc4 = (tid >> 4) * 4;  // B stage 4x4 block

  for (int k0 = 0; k0 < NC; k0 += 64) {
    {  // A: natural copy, fp32 -> bf16
      const float4* src = (const float4*)(wqkv + (size_t)(m0 + ar) * NC + k0 + as);
      float4 v0 = src[0], v1 = src[1], v2 = src[2], v3 = src[3];
      bf16x8 w0, w1;
      w0[0]=tob(v0.x); w0[1]=tob(v0.y); w0[2]=tob(v0.z); w0[3]=tob(v0.w);
      w0[4]=tob(v1.x); w0[5]=tob(v1.y); w0[6]=tob(v1.z); w0[7]=tob(v1.w);
      w1[0]=tob(v2.x); w1[1]=tob(v2.y); w1[2]=tob(v2.z); w1[3]=tob(v2.w);
      w1[4]=tob(v3.x); w1[5]=tob(v3.y); w1[6]=tob(v3.z); w1[7]=tob(v3.w);
      *(bf16x8*)&lA[ar][as]     = w0;
      *(bf16x8*)&lA[ar][as + 8] = w1;
    }
    {  // B: x[c][n] --GN--> lB[n][c] (in-register 4x4 transpose)
      float vr[4][4];
#pragma unroll
      for (int r = 0; r < 4; ++r) {
        const int c = k0 + tc4 + r;
        const float ca = coefA[b * NC + c], cb = coefB[b * NC + c];
        float4 v = *(const float4*)(x + (size_t)(b * NC + c) * NSPA + n0 + tn4);
        vr[r][0] = v.x * ca + cb; vr[r][1] = v.y * ca + cb;
        vr[r][2] = v.z * ca + cb; vr[r][3] = v.w * ca + cb;
      }
#pragma unroll
      for (int j = 0; j < 4; ++j) {
        bf16x4 w;
        w[0] = tob(vr[0][j]); w[1] = tob(vr[1][j]);
        w[2] = tob(vr[2][j]); w[3] = tob(vr[3][j]);
        *(bf16x4*)&lB[tn4 + j][tc4] = w;
      }
    }
    __syncthreads();
    mfma_tile(lA, lB, wm, wn, lane, acc);
    __syncthreads();
  }
  const int fr = lane & 15, fg4 = (lane >> 4) * 4;
#pragma unroll
  for (int ti = 0; ti < 2; ++ti)
#pragma unroll
    for (int tj = 0; tj < 2; ++tj) {
      const int m = m0 + wm + ti * 16 + fg4;
      const int n = n0 + wn + tj * 16 + fr;
#pragma unroll
      for (int r = 0; r < 4; ++r)
        qkv[((size_t)b * NO3 + m + r) * NSPA + n] = tob(acc[ti][tj][r] + bqkv[m + r]);
    }
}

// ---------------------------------------------------------------------------
// K3: P[b][i][j] = (sum_d q[d][i]*k[d][j]) * c^-0.5, bf16.  grid (16,16,B)
// ---------------------------------------------------------------------------
__global__ void scores_kernel(const __bf16* __restrict__ qkv, __bf16* __restrict__ P) {
  const int j0 = blockIdx.x * 64;
  const int i0 = blockIdx.y * 64;
  const int b  = blockIdx.z;
  const __bf16* qb = qkv + (size_t)b * NO3 * NSPA;        // q at o=0, [d][i]
  const __bf16* kb = qb + (size_t)NC * NSPA;              // k at o=C, [d][j]
  __shared__ __bf16 lA[64][72];  // [i][d]
  __shared__ __bf16 lB[64][72];  // [j][d]
  const int tid = threadIdx.x;
  const int lane = tid & 63, wave = tid >> 6;
  const int wm = (wave >> 1) * 32, wn = (wave & 1) * 32;
  f32x4 acc[2][2] = {};
  const int t4 = (tid & 15) * 4;   // i/j offset
  const int d4 = (tid >> 4) * 4;   // d offset

  for (int k0 = 0; k0 < NC; k0 += 64) {
    bf16x4 ra[4], rb[4];
#pragma unroll
    for (int r = 0; r < 4; ++r) {
      ra[r] = *(const bf16x4*)(qb + (size_t)(k0 + d4 + r) * NSPA + i0 + t4);
      rb[r] = *(const bf16x4*)(kb + (size_t)(k0 + d4 + r) * NSPA + j0 + t4);
    }
#pragma unroll
    for (int j = 0; j < 4; ++j) {
      bf16x4 wa, wb;
      wa[0]=ra[0][j]; wa[1]=ra[1][j]; wa[2]=ra[2][j]; wa[3]=ra[3][j];
      wb[0]=rb[0][j]; wb[1]=rb[1][j]; wb[2]=rb[2][j]; wb[3]=rb[3][j];
      *(bf16x4*)&lA[t4 + j][d4] = wa;
      *(bf16x4*)&lB[t4 + j][d4] = wb;
    }
    __syncthreads();
    mfma_tile(lA, lB, wm, wn, lane, acc);
    __syncthreads();
  }
  const int fr = lane & 15, fg4 = (lane >> 4) * 4;
#pragma unroll
  for (int ti = 0; ti < 2; ++ti)
#pragma unroll
    for (int tj = 0; tj < 2; ++tj) {
      const int i = i0 + wm + ti * 16 + fg4;
      const int j = j0 + wn + tj * 16 + fr;
#pragma unroll
      for (int r = 0; r < 4; ++r)
        P[((size_t)b * NSPA + i + r) * NSPA + j] = tob(acc[ti][tj][r] * SCL);
    }
}

// ---------------------------------------------------------------------------
// K4: in-place row softmax on bf16 P. grid = B*N rows, 256 thr (4 elems each)
// ---------------------------------------------------------------------------
__global__ void softmax_kernel(__bf16* __restrict__ P) {
  const int row = blockIdx.x;
  __bf16* p = P + (size_t)row * NSPA;
  const int tid = threadIdx.x;
  bf16x4 v = *((const bf16x4*)p + tid);
  float f0 = (float)v[0], f1 = (float)v[1], f2 = (float)v[2], f3 = (float)v[3];
  float m = fmaxf(fmaxf(f0, f1), fmaxf(f2, f3));
#pragma unroll
  for (int off = 32; off; off >>= 1) m = fmaxf(m, __shfl_xor(m, off));
  __shared__ float red[4];
  const int wave = tid >> 6, lane = tid & 63;
  if (lane == 0) red[wave] = m;
  __syncthreads();
  m = fmaxf(fmaxf(red[0], red[1]), fmaxf(red[2], red[3]));
  float e0 = __expf(f0 - m), e1 = __expf(f1 - m), e2 = __expf(f2 - m), e3 = __expf(f3 - m);
  float s = (e0 + e1) + (e2 + e3);
#pragma unroll
  for (int off = 32; off; off >>= 1) s += __shfl_xor(s, off);
  __syncthreads();
  if (lane == 0) red[wave] = s;
  __syncthreads();
  s = (red[0] + red[1]) + (red[2] + red[3]);
  const float inv = 1.f / s;
  v[0] = tob(e0 * inv); v[1] = tob(e1 * inv); v[2] = tob(e2 * inv); v[3] = tob(e3 * inv);
  *((bf16x4*)p + tid) = v;
}

// ---------------------------------------------------------------------------
// K5: attn[b][d][i] = sum_j V[d][j] * P[i][j] -> written into q-region of qkv
// grid (16, 8, B). Both operands stage naturally ([out][k] already).
// ---------------------------------------------------------------------------
__global__ void pv_kernel(const __bf16* __restrict__ qkv, const __bf16* __restrict__ P,
                          __bf16* __restrict__ attn /* == qkv q-region, [b][NO3][n] */) {
  const int i0 = blockIdx.x * 64;
  const int d0 = blockIdx.y * 64;
  const int b  = blockIdx.z;
  const __bf16* vb = qkv + (size_t)b * NO3 * NSPA + (size_t)2 * NC * NSPA;  // v, [d][j]
  const __bf16* pb = P + (size_t)b * NSPA * NSPA;                           // [i][j]
  __shared__ __bf16 lA[64][72];  // [d][j]
  __shared__ __bf16 lB[64][72];  // [i][j]
  const int tid = threadIdx.x;
  const int lane = tid & 63, wave = tid >> 6;
  const int wm = (wave >> 1) * 32, wn = (wave & 1) * 32;
  f32x4 acc[2][2] = {};
  const int ar = tid >> 2, as = (tid & 3) * 16;

  for (int k0 = 0; k0 < NSPA; k0 += 64) {
    const bf16x8* sa = (const bf16x8*)(vb + (size_t)(d0 + ar) * NSPA + k0 + as);
    const bf16x8* sb = (const bf16x8*)(pb + (size_t)(i0 + ar) * NSPA + k0 + as);
    *(bf16x8*)&lA[ar][as]     = sa[0];
    *(bf16x8*)&lA[ar][as + 8] = sa[1];
    *(bf16x8*)&lB[ar][as]     = sb[0];
    *(bf16x8*)&lB[ar][as + 8] = sb[1];
    __syncthreads();
    mfma_tile(lA, lB, wm, wn, lane, acc);
    __syncthreads();
  }
  const int fr = lane & 15, fg4 = (lane >> 4) * 4;
#pragma unroll
  for (int ti = 0; ti < 2; ++ti)
#pragma unroll
    for (int tj = 0; tj < 2; ++tj) {
      const int d = d0 + wm + ti * 16 + fg4;
      const int i = i0 + wn + tj * 16 + fr;
#pragma unroll
      for (int r = 0; r < 4; ++r)
        attn[((size_t)b * NO3 + d + r) * NSPA + i] = tob(acc[ti][tj][r]);
    }
}

// ---------------------------------------------------------------------------
// K6: out[b][o][n] = sum_c Wout[o][c]*attn[c][n] + bout[o] + x[b][o][n], fp32
// grid (16, 8, B)
// ---------------------------------------------------------------------------
__global__ void out_gemm_kernel(const __bf16* __restrict__ attn,
                                const float* __restrict__ wout,
                                const float* __restrict__ bout,
                                const float* __restrict__ x,
                                float* __restrict__ out) {
  const int n0 = blockIdx.x * 64;
  const int m0 = blockIdx.y * 64;
  const int b  = blockIdx.z;
  const __bf16* ab = attn + (size_t)b * NO3 * NSPA;  // [c][n] rows (batch stride NO3)
  __shared__ __bf16 lA[64][72];  // [o][c]
  __shared__ __bf16 lB[64][72];  // [n][c]
  const int tid = threadIdx.x;
  const int lane = tid & 63, wave = tid >> 6;
  const int wm = (wave >> 1) * 32, wn = (wave & 1) * 32;
  f32x4 acc[2][2] = {};
  const int ar = tid >> 2, as = (tid & 3) * 16;
  const int t4 = (tid & 15) * 4, d4 = (tid >> 4) * 4;

  for (int k0 = 0; k0 < NC; k0 += 64) {
    {  // A: Wout natural, fp32 -> bf16
      const float4* src = (const float4*)(wout + (size_t)(m0 + ar) * NC + k0 + as);
      float4 v0 = src[0], v1 = src[1], v2 = src[2], v3 = src[3];
      bf16x8 w0, w1;
      w0[0]=tob(v0.x); w0[1]=tob(v0.y); w0[2]=tob(v0.z); w0[3]=tob(v0.w);
      w0[4]=tob(v1.x); w0[5]=tob(v1.y); w0[6]=tob(v1.z); w0[7]=tob(v1.w);
      w1[0]=tob(v2.x); w1[1]=tob(v2.y); w1[2]=tob(v2.z); w1[3]=tob(v2.w);
      w1[4]=tob(v3.x); w1[5]=tob(v3.y); w1[6]=tob(v3.z); w1[7]=tob(v3.w);
      *(bf16x8*)&lA[ar][as]     = w0;
      *(bf16x8*)&lA[ar][as + 8] = w1;
    }
    {  // B: attn [c][n] -> lB[n][c] transpose
      bf16x4 rb[4];
#pragma unroll
      for (int r = 0; r < 4; ++r)
        rb[r] = *(const bf16x4*)(ab + (size_t)(k0 + d4 + r) * NSPA + n0 + t4);
#pragma unroll
      for (int j = 0; j < 4; ++j) {
        bf16x4 w;
        w[0]=rb[0][j]; w[1]=rb[1][j]; w[2]=rb[2][j]; w[3]=rb[3][j];
        *(bf16x4*)&lB[t4 + j][d4] = w;
      }
    }
    __syncthreads();
    mfma_tile(lA, lB, wm, wn, lane, acc);
    __syncthreads();
  }
  const int fr = lane & 15, fg4 = (lane >> 4) * 4;
#pragma unroll
  for (int ti = 0; ti < 2; ++ti)
#pragma unroll
    for (int tj = 0; tj < 2; ++tj) {
      const int m = m0 + wm + ti * 16 + fg4;
      const int n = n0 + wn + tj * 16 + fr;
#pragma unroll
      for (int r = 0; r < 4; ++r) {
        const size_t idx = ((size_t)b * NC + m + r) * NSPA + n;
        out[idx] = acc[ti][tj][r] + bout[m + r] + x[idx];
      }
    }
}

// ---------------------------------------------------------------------------
// Workspace layout (needs ~80.1 MB):
//   [0, 64KB)              coefA/coefB (B*C floats each)
//   [64KB, +48MB)          qkv bf16 [B][1536][1024]; q-region reused for attn
//   [+48MB, +32MB)         P bf16 [B][1024][1024] (scores -> softmax in place)
// ---------------------------------------------------------------------------
extern "C" void kernel_launch(void* const* d_in, const int* in_sizes, int n_in,
                              void* d_out, int out_size, void* d_ws, size_t ws_size,
                              hipStream_t stream) {
  const float* x        = (const float*)d_in[0];
  // d_in[1] = time_emb, d_in[2] = y: unused by the reference
  const float* gn_scale = (const float*)d_in[3];
  const float* gn_bias  = (const float*)d_in[4];
  const float* w_qkv    = (const float*)d_in[5];
  const float* b_qkv    = (const float*)d_in[6];
  const float* w_out    = (const float*)d_in[7];
  const float* b_out    = (const float*)d_in[8];
  float* out = (float*)d_out;

  char* ws = (char*)d_ws;
  float* coefA = (float*)ws;
  float* coefB = coefA + NB * NC;
  __bf16* qkv = (__bf16*)(ws + (64 << 10));
  __bf16* P   = (__bf16*)(ws + (64 << 10) + (size_t)NB * NO3 * NSPA * sizeof(__bf16));

  gn_stats_kernel<<<dim3(NB * NG), 256, 0, stream>>>(x, gn_scale, gn_bias, coefA, coefB);
  qkv_gemm_kernel<<<dim3(16, 24, NB), 256, 0, stream>>>(x, w_qkv, b_qkv, coefA, coefB, qkv);
  scores_kernel<<<dim3(16, 16, NB), 256, 0, stream>>>(qkv, P);
  softmax_kernel<<<dim3(NB * NSPA), 256, 0, stream>>>(P);
  pv_kernel<<<dim3(16, 8, NB), 256, 0, stream>>>(qkv, P, qkv /* attn -> q region */);
  out_gemm_kernel<<<dim3(16, 8, NB), 256, 0, stream>>>(qkv, w_out, b_out, x, out);
}

// Round 2
// 175.546 us; speedup vs baseline: 1.4534x; 1.4534x over previous
//
#include <hip/hip_runtime.h>
#include <hip/hip_bf16.h>

// Shapes (fixed by the problem)
#define NB   16    // batch
#define NC   512   // channels
#define NSPA 1024  // h*w
#define NO3  1536  // 3*C
#define GN_EPS 1e-5f
#define SCL 0.044194173824159216f  // 512^-0.5

typedef __bf16 bf16x8 __attribute__((ext_vector_type(8)));
typedef __bf16 bf16x4 __attribute__((ext_vector_type(4)));
typedef float  f32x4  __attribute__((ext_vector_type(4)));

typedef __attribute__((address_space(3))) void lds_t;
typedef const __attribute__((address_space(1))) void gl_t;
#define GLDS16(g, l) __builtin_amdgcn_global_load_lds((gl_t*)(g), (lds_t*)(l), 16, 0, 0)

__device__ __forceinline__ __bf16 tob(float f) { return (__bf16)f; }

// ---------------------------------------------------------------------------
// K1: GroupNorm stats -> per (b,c) affine coefs: xn = x*coefA + coefB
// ---------------------------------------------------------------------------
__global__ void gn_stats_kernel(const float* __restrict__ x,
                                const float* __restrict__ gn_scale,
                                const float* __restrict__ gn_bias,
                                float* __restrict__ coefA,
                                float* __restrict__ coefB) {
  const int bg = blockIdx.x;
  const int b = bg >> 5, g = bg & 31;
  const float4* base = (const float4*)(x + (size_t)(b * NC + g * 16) * NSPA);
  const int tid = threadIdx.x;
  float s = 0.f, ss = 0.f;
#pragma unroll
  for (int i = 0; i < 16; ++i) {
    float4 v = base[i * 256 + tid];
    s  += (v.x + v.y) + (v.z + v.w);
    ss += (v.x * v.x + v.y * v.y) + (v.z * v.z + v.w * v.w);
  }
#pragma unroll
  for (int off = 32; off; off >>= 1) {
    s  += __shfl_xor(s, off);
    ss += __shfl_xor(ss, off);
  }
  __shared__ float rs[4], rss[4];
  const int wave = tid >> 6, lane = tid & 63;
  if (lane == 0) { rs[wave] = s; rss[wave] = ss; }
  __syncthreads();
  if (tid < 16) {
    float S  = rs[0] + rs[1] + rs[2] + rs[3];
    float SS = rss[0] + rss[1] + rss[2] + rss[3];
    float mean = S * (1.f / 16384.f);
    float var  = SS * (1.f / 16384.f) - mean * mean;
    float rstd = rsqrtf(var + GN_EPS);
    int c = g * 16 + tid;
    float a = gn_scale[c] * rstd;
    coefA[b * NC + c] = a;
    coefB[b * NC + c] = gn_bias[c] - mean * a;
  }
}

// ---------------------------------------------------------------------------
// K2a: pack weights fp32 -> bf16, natural [o][c]
// ---------------------------------------------------------------------------
__global__ void pack_w_kernel(const float* __restrict__ wq, const float* __restrict__ wo,
                              __bf16* __restrict__ wqb, __bf16* __restrict__ wob) {
  const int t = blockIdx.x * 256 + threadIdx.x;
  const int NQ = NO3 * NC / 4;
  float4 v;
  __bf16* dst;
  if (t < NQ) { v = ((const float4*)wq)[t]; dst = wqb + (size_t)t * 4; }
  else        { v = ((const float4*)wo)[t - NQ]; dst = wob + (size_t)(t - NQ) * 4; }
  bf16x4 w;
  w[0] = tob(v.x); w[1] = tob(v.y); w[2] = tob(v.z); w[3] = tob(v.w);
  *(bf16x4*)dst = w;
}

// ---------------------------------------------------------------------------
// K2b: xnT[b][n][c] = bf16(GN(x))  (64c x 64n LDS transpose tiles)
// grid (NSPA/64, NC/64, NB)
// ---------------------------------------------------------------------------
__global__ void pack_x_kernel(const float* __restrict__ x,
                              const float* __restrict__ coefA,
                              const float* __restrict__ coefB,
                              __bf16* __restrict__ xnT) {
  const int n0 = blockIdx.x * 64, c0 = blockIdx.y * 64, b = blockIdx.z;
  __shared__ __bf16 l[64][72];  // [n][c]
  const int tid = threadIdx.x;
  const int cl = tid >> 2, seg = (tid & 3) * 16;
  const float ca = coefA[b * NC + c0 + cl], cb = coefB[b * NC + c0 + cl];
  const float4* src = (const float4*)(x + (size_t)(b * NC + c0 + cl) * NSPA + n0 + seg);
#pragma unroll
  for (int i = 0; i < 4; ++i) {
    float4 v = src[i];
    l[seg + i * 4 + 0][cl] = tob(v.x * ca + cb);
    l[seg + i * 4 + 1][cl] = tob(v.y * ca + cb);
    l[seg + i * 4 + 2][cl] = tob(v.z * ca + cb);
    l[seg + i * 4 + 3][cl] = tob(v.w * ca + cb);
  }
  __syncthreads();
#pragma unroll
  for (int i = 0; i < 2; ++i) {
    const int chunk = tid + i * 256;
    const int row = chunk >> 3, s = chunk & 7;
    *(bf16x8*)(xnT + (size_t)(b * NSPA + n0 + row) * NC + c0 + s * 8) =
        *(const bf16x8*)&l[row][s * 8];
  }
}

// ---------------------------------------------------------------------------
// m97-style GEMM core: 128x128 tile, BK=64, 256 thr (4 waves 2x2, 64x64/wave,
// 4x4 frags). A,B both [out][k]-major bf16; staged via global_load_lds x16.
// ---------------------------------------------------------------------------
__device__ __forceinline__ void gemm_core(const __bf16* __restrict__ A, int lda,
                                          const __bf16* __restrict__ B, int ldb,
                                          int K, __bf16 (*lA)[64], __bf16 (*lB)[64],
                                          f32x4 acc[4][4]) {
  const int tid = threadIdx.x;
  const int lane = tid & 63, wave = tid >> 6;
  const int wm = (wave >> 1) * 64, wn = (wave & 1) * 64;
  const int fr = lane & 15, fg = (lane >> 4) * 8;
  const int srow = tid >> 3, sseg = (tid & 7) * 8;  // staging: 16B chunk per thread
  __bf16* lAf = &lA[0][0];
  __bf16* lBf = &lB[0][0];

  for (int k0 = 0; k0 < K; k0 += 64) {
#pragma unroll
    for (int i = 0; i < 4; ++i) {
      GLDS16(A + (size_t)(srow + i * 32) * lda + k0 + sseg, lAf + (tid + i * 256) * 8);
      GLDS16(B + (size_t)(srow + i * 32) * ldb + k0 + sseg, lBf + (tid + i * 256) * 8);
    }
    __syncthreads();
#pragma unroll
    for (int ks = 0; ks < 2; ++ks) {
      bf16x8 af[4], bfr[4];
#pragma unroll
      for (int mi = 0; mi < 4; ++mi)
        af[mi] = *(const bf16x8*)&lA[wm + mi * 16 + fr][ks * 32 + fg];
#pragma unroll
      for (int ni = 0; ni < 4; ++ni)
        bfr[ni] = *(const bf16x8*)&lB[wn + ni * 16 + fr][ks * 32 + fg];
#pragma unroll
      for (int mi = 0; mi < 4; ++mi)
#pragma unroll
        for (int ni = 0; ni < 4; ++ni)
          acc[mi][ni] = __builtin_amdgcn_mfma_f32_16x16x32_bf16(af[mi], bfr[ni], acc[mi][ni], 0, 0, 0);
    }
    __syncthreads();
  }
}

// ---------------------------------------------------------------------------
// K3: QKV GEMM. C[o][n] = Wqkv[o][c] x xnT[n][c]^T (+bias).
//   o <  1024 (q,k): transposed store -> qk[b][n][o]   (bf16x4, contiguous)
//   o >= 1024 (v)  : natural store    -> v[b][o-1024][n]
// grid (8, 12, NB)
// ---------------------------------------------------------------------------
__global__ __launch_bounds__(256) void qkv_gemm_kernel(
    const __bf16* __restrict__ wqb, const __bf16* __restrict__ xnT,
    const float* __restrict__ bqkv, __bf16* __restrict__ qk, __bf16* __restrict__ v) {
  const int n0 = blockIdx.x * 128, m0 = blockIdx.y * 128, b = blockIdx.z;
  __shared__ __bf16 lA[128][64], lB[128][64];
  f32x4 acc[4][4] = {};
  gemm_core(wqb + (size_t)m0 * NC, NC, xnT + ((size_t)b * NSPA + n0) * NC, NC, NC, lA, lB, acc);

  const int lane = threadIdx.x & 63, wave = threadIdx.x >> 6;
  const int wm = (wave >> 1) * 64, wn = (wave & 1) * 64;
  const int fr = lane & 15, fq4 = (lane >> 4) * 4;
  if (m0 < NSPA) {
#pragma unroll
    for (int mi = 0; mi < 4; ++mi) {
      const int m = m0 + wm + mi * 16 + fq4;
      const float4 bias = *(const float4*)(bqkv + m);
#pragma unroll
      for (int ni = 0; ni < 4; ++ni) {
        const int n = n0 + wn + ni * 16 + fr;
        bf16x4 w;
        w[0] = tob(acc[mi][ni][0] + bias.x);
        w[1] = tob(acc[mi][ni][1] + bias.y);
        w[2] = tob(acc[mi][ni][2] + bias.z);
        w[3] = tob(acc[mi][ni][3] + bias.w);
        *(bf16x4*)(qk + ((size_t)b * NSPA + n) * NSPA + m) = w;
      }
    }
  } else {
#pragma unroll
    for (int mi = 0; mi < 4; ++mi) {
      const int m = m0 + wm + mi * 16 + fq4;        // o index (>=1024)
      const float4 bias = *(const float4*)(bqkv + m);
      const int vr = m - NSPA;
#pragma unroll
      for (int ni = 0; ni < 4; ++ni) {
        const int n = n0 + wn + ni * 16 + fr;
        v[((size_t)b * NC + vr + 0) * NSPA + n] = tob(acc[mi][ni][0] + bias.x);
        v[((size_t)b * NC + vr + 1) * NSPA + n] = tob(acc[mi][ni][1] + bias.y);
        v[((size_t)b * NC + vr + 2) * NSPA + n] = tob(acc[mi][ni][2] + bias.z);
        v[((size_t)b * NC + vr + 3) * NSPA + n] = tob(acc[mi][ni][3] + bias.w);
      }
    }
  }
}

// ---------------------------------------------------------------------------
// K4: scores (swapped). C[j][i] = k[j][d] . q[i][d]; store P[b][i][j] * SCL.
// q rows = qk[b][i][0..511], k rows = qk[b][j][512..1023]. grid (8, 8, NB)
// ---------------------------------------------------------------------------
__global__ __launch_bounds__(256) void scores_kernel(const __bf16* __restrict__ qk,
                                                     __bf16* __restrict__ P) {
  const int i0 = blockIdx.x * 128, j0 = blockIdx.y * 128, b = blockIdx.z;
  const __bf16* base = qk + (size_t)b * NSPA * NSPA;
  __shared__ __bf16 lA[128][64], lB[128][64];
  f32x4 acc[4][4] = {};
  gemm_core(base + (size_t)j0 * NSPA + NC, NSPA, base + (size_t)i0 * NSPA, NSPA, NC, lA, lB, acc);

  const int lane = threadIdx.x & 63, wave = threadIdx.x >> 6;
  const int wm = (wave >> 1) * 64, wn = (wave & 1) * 64;
  const int fr = lane & 15, fq4 = (lane >> 4) * 4;
#pragma unroll
  for (int mi = 0; mi < 4; ++mi) {
    const int j = j0 + wm + mi * 16 + fq4;
#pragma unroll
    for (int ni = 0; ni < 4; ++ni) {
      const int i = i0 + wn + ni * 16 + fr;
      bf16x4 w;
      w[0] = tob(acc[mi][ni][0] * SCL);
      w[1] = tob(acc[mi][ni][1] * SCL);
      w[2] = tob(acc[mi][ni][2] * SCL);
      w[3] = tob(acc[mi][ni][3] * SCL);
      *(bf16x4*)(P + ((size_t)b * NSPA + i) * NSPA + j) = w;
    }
  }
}

// ---------------------------------------------------------------------------
// K5: in-place row softmax on bf16 P. grid = NB*NSPA rows, 256 thr
// ---------------------------------------------------------------------------
__global__ void softmax_kernel(__bf16* __restrict__ P) {
  const int row = blockIdx.x;
  __bf16* p = P + (size_t)row * NSPA;
  const int tid = threadIdx.x;
  bf16x4 v = *((const bf16x4*)p + tid);
  float f0 = (float)v[0], f1 = (float)v[1], f2 = (float)v[2], f3 = (float)v[3];
  float m = fmaxf(fmaxf(f0, f1), fmaxf(f2, f3));
#pragma unroll
  for (int off = 32; off; off >>= 1) m = fmaxf(m, __shfl_xor(m, off));
  __shared__ float red[4];
  const int wave = tid >> 6, lane = tid & 63;
  if (lane == 0) red[wave] = m;
  __syncthreads();
  m = fmaxf(fmaxf(red[0], red[1]), fmaxf(red[2], red[3]));
  float e0 = __expf(f0 - m), e1 = __expf(f1 - m), e2 = __expf(f2 - m), e3 = __expf(f3 - m);
  float s = (e0 + e1) + (e2 + e3);
#pragma unroll
  for (int off = 32; off; off >>= 1) s += __shfl_xor(s, off);
  __syncthreads();
  if (lane == 0) red[wave] = s;
  __syncthreads();
  s = (red[0] + red[1]) + (red[2] + red[3]);
  const float inv = 1.f / s;
  v[0] = tob(e0 * inv); v[1] = tob(e1 * inv); v[2] = tob(e2 * inv); v[3] = tob(e3 * inv);
  *((bf16x4*)p + tid) = v;
}

// ---------------------------------------------------------------------------
// K6: PV. C[d][i] = v[d][j] . P[i][j]; transposed store -> attn[b][i][d].
// grid (8, 4, NB), K=1024
// ---------------------------------------------------------------------------
__global__ __launch_bounds__(256) void pv_kernel(const __bf16* __restrict__ v,
                                                 const __bf16* __restrict__ P,
                                                 __bf16* __restrict__ attn) {
  const int i0 = blockIdx.x * 128, d0 = blockIdx.y * 128, b = blockIdx.z;
  __shared__ __bf16 lA[128][64], lB[128][64];
  f32x4 acc[4][4] = {};
  gemm_core(v + ((size_t)b * NC + d0) * NSPA, NSPA,
            P + ((size_t)b * NSPA + i0) * NSPA, NSPA, NSPA, lA, lB, acc);

  const int lane = threadIdx.x & 63, wave = threadIdx.x >> 6;
  const int wm = (wave >> 1) * 64, wn = (wave & 1) * 64;
  const int fr = lane & 15, fq4 = (lane >> 4) * 4;
#pragma unroll
  for (int mi = 0; mi < 4; ++mi) {
    const int d = d0 + wm + mi * 16 + fq4;
#pragma unroll
    for (int ni = 0; ni < 4; ++ni) {
      const int i = i0 + wn + ni * 16 + fr;
      bf16x4 w;
      w[0] = tob(acc[mi][ni][0]);
      w[1] = tob(acc[mi][ni][1]);
      w[2] = tob(acc[mi][ni][2]);
      w[3] = tob(acc[mi][ni][3]);
      *(bf16x4*)(attn + ((size_t)b * NSPA + i) * NC + d) = w;
    }
  }
}

// ---------------------------------------------------------------------------
// K7: out-proj. C[o][n] = Wout[o][c] . attn[n][c] + bias + x, fp32 natural.
// grid (8, 4, NB)
// ---------------------------------------------------------------------------
__global__ __launch_bounds__(256) void out_gemm_kernel(
    const __bf16* __restrict__ wob, const __bf16* __restrict__ attn,
    const float* __restrict__ bout, const float* __restrict__ x,
    float* __restrict__ out) {
  const int n0 = blockIdx.x * 128, m0 = blockIdx.y * 128, b = blockIdx.z;
  __shared__ __bf16 lA[128][64], lB[128][64];
  f32x4 acc[4][4] = {};
  gemm_core(wob + (size_t)m0 * NC, NC, attn + ((size_t)b * NSPA + n0) * NC, NC, NC, lA, lB, acc);

  const int lane = threadIdx.x & 63, wave = threadIdx.x >> 6;
  const int wm = (wave >> 1) * 64, wn = (wave & 1) * 64;
  const int fr = lane & 15, fq4 = (lane >> 4) * 4;
#pragma unroll
  for (int mi = 0; mi < 4; ++mi) {
    const int m = m0 + wm + mi * 16 + fq4;
    const float4 bias = *(const float4*)(bout + m);
#pragma unroll
    for (int ni = 0; ni < 4; ++ni) {
      const int n = n0 + wn + ni * 16 + fr;
      const size_t i0x = ((size_t)b * NC + m) * NSPA + n;
      out[i0x + 0 * NSPA] = acc[mi][ni][0] + bias.x + x[i0x + 0 * NSPA];
      out[i0x + 1 * NSPA] = acc[mi][ni][1] + bias.y + x[i0x + 1 * NSPA];
      out[i0x + 2 * NSPA] = acc[mi][ni][2] + bias.z + x[i0x + 2 * NSPA];
      out[i0x + 3 * NSPA] = acc[mi][ni][3] + bias.w + x[i0x + 3 * NSPA];
    }
  }
}

// ---------------------------------------------------------------------------
// Workspace (~66 MB):
//   coefA/coefB:      2 x 32 KB
//   xnT / attn:       16 MB  (xnT dead after qkv_gemm; pv writes attn here)
//   wqb:              1.5 MB    wob: 0.5 MB
//   v:                16 MB
//   P:                32 MB
// qk (32 MB) lives in d_out (33.5 MB fp32) — dead before out_gemm writes.
// ---------------------------------------------------------------------------
extern "C" void kernel_launch(void* const* d_in, const int* in_sizes, int n_in,
                              void* d_out, int out_size, void* d_ws, size_t ws_size,
                              hipStream_t stream) {
  const float* x        = (const float*)d_in[0];
  const float* gn_scale = (const float*)d_in[3];
  const float* gn_bias  = (const float*)d_in[4];
  const float* w_qkv    = (const float*)d_in[5];
  const float* b_qkv    = (const float*)d_in[6];
  const float* w_out    = (const float*)d_in[7];
  const float* b_out    = (const float*)d_in[8];
  float* out = (float*)d_out;

  char* ws = (char*)d_ws;
  float*  coefA = (float*)ws;                                   // 32 KB
  float*  coefB = coefA + NB * NC;                              // 32 KB
  __bf16* xnT   = (__bf16*)(ws + (64 << 10));                   // 16 MB (also attn)
  __bf16* attn  = xnT;
  __bf16* wqb   = xnT + (size_t)NB * NSPA * NC;                 // 1.5 MB
  __bf16* wob   = wqb + (size_t)NO3 * NC;                       // 0.5 MB
  __bf16* vbuf  = wob + (size_t)NC * NC;                        // 16 MB
  __bf16* P     = vbuf + (size_t)NB * NC * NSPA;                // 32 MB
  __bf16* qk    = (__bf16*)d_out;                               // 32 MB scratch in out

  gn_stats_kernel<<<dim3(NB * 32), 256, 0, stream>>>(x, gn_scale, gn_bias, coefA, coefB);
  pack_w_kernel<<<dim3((NO3 * NC + NC * NC) / 4 / 256), 256, 0, stream>>>(w_qkv, w_out, wqb, wob);
  pack_x_kernel<<<dim3(NSPA / 64, NC / 64, NB), 256, 0, stream>>>(x, coefA, coefB, xnT);
  qkv_gemm_kernel<<<dim3(8, 12, NB), 256, 0, stream>>>(wqb, xnT, b_qkv, qk, vbuf);
  scores_kernel<<<dim3(8, 8, NB), 256, 0, stream>>>(qk, P);
  softmax_kernel<<<dim3(NB * NSPA), 256, 0, stream>>>(P);
  pv_kernel<<<dim3(8, 4, NB), 256, 0, stream>>>(vbuf, P, attn);
  out_gemm_kernel<<<dim3(8, 4, NB), 256, 0, stream>>>(wob, attn, b_out, x, out);
}

// Round 3
// 156.392 us; speedup vs baseline: 1.6314x; 1.1225x over previous
//
#include <hip/hip_runtime.h>
#include <hip/hip_bf16.h>

// Shapes (fixed by the problem)
#define NB   16    // batch
#define NC   512   // channels
#define NSPA 1024  // h*w
#define NO3  1536  // 3*C
#define GN_EPS 1e-5f
#define SCL 0.044194173824159216f  // 512^-0.5

typedef __bf16 bf16x8 __attribute__((ext_vector_type(8)));
typedef __bf16 bf16x4 __attribute__((ext_vector_type(4)));
typedef float  f32x4  __attribute__((ext_vector_type(4)));

typedef __attribute__((address_space(3))) void lds_t;
typedef const __attribute__((address_space(1))) void gl_t;
#define GLDS16(g, l) __builtin_amdgcn_global_load_lds((gl_t*)(g), (lds_t*)(l), 16, 0, 0)

__device__ __forceinline__ __bf16 tob(float f) { return (__bf16)f; }

// ---------------------------------------------------------------------------
// K1: GroupNorm stats -> per (b,c) affine coefs: xn = x*coefA + coefB
// ---------------------------------------------------------------------------
__global__ void gn_stats_kernel(const float* __restrict__ x,
                                const float* __restrict__ gn_scale,
                                const float* __restrict__ gn_bias,
                                float* __restrict__ coefA,
                                float* __restrict__ coefB) {
  const int bg = blockIdx.x;
  const int b = bg >> 5, g = bg & 31;
  const float4* base = (const float4*)(x + (size_t)(b * NC + g * 16) * NSPA);
  const int tid = threadIdx.x;
  float s = 0.f, ss = 0.f;
#pragma unroll
  for (int i = 0; i < 16; ++i) {
    float4 v = base[i * 256 + tid];
    s  += (v.x + v.y) + (v.z + v.w);
    ss += (v.x * v.x + v.y * v.y) + (v.z * v.z + v.w * v.w);
  }
#pragma unroll
  for (int off = 32; off; off >>= 1) {
    s  += __shfl_xor(s, off);
    ss += __shfl_xor(ss, off);
  }
  __shared__ float rs[4], rss[4];
  const int wave = tid >> 6, lane = tid & 63;
  if (lane == 0) { rs[wave] = s; rss[wave] = ss; }
  __syncthreads();
  if (tid < 16) {
    float S  = rs[0] + rs[1] + rs[2] + rs[3];
    float SS = rss[0] + rss[1] + rss[2] + rss[3];
    float mean = S * (1.f / 16384.f);
    float var  = SS * (1.f / 16384.f) - mean * mean;
    float rstd = rsqrtf(var + GN_EPS);
    int c = g * 16 + tid;
    float a = gn_scale[c] * rstd;
    coefA[b * NC + c] = a;
    coefB[b * NC + c] = gn_bias[c] - mean * a;
  }
}

// ---------------------------------------------------------------------------
// K2a: pack weights fp32 -> bf16, natural [o][c]
// ---------------------------------------------------------------------------
__global__ void pack_w_kernel(const float* __restrict__ wq, const float* __restrict__ wo,
                              __bf16* __restrict__ wqb, __bf16* __restrict__ wob) {
  const int t = blockIdx.x * 256 + threadIdx.x;
  const int NQ = NO3 * NC / 4;
  float4 v;
  __bf16* dst;
  if (t < NQ) { v = ((const float4*)wq)[t]; dst = wqb + (size_t)t * 4; }
  else        { v = ((const float4*)wo)[t - NQ]; dst = wob + (size_t)(t - NQ) * 4; }
  bf16x4 w;
  w[0] = tob(v.x); w[1] = tob(v.y); w[2] = tob(v.z); w[3] = tob(v.w);
  *(bf16x4*)dst = w;
}

// ---------------------------------------------------------------------------
// K2b: xnT[b][n][c] = bf16(GN(x))  (64c x 64n LDS transpose tiles)
// ---------------------------------------------------------------------------
__global__ void pack_x_kernel(const float* __restrict__ x,
                              const float* __restrict__ coefA,
                              const float* __restrict__ coefB,
                              __bf16* __restrict__ xnT) {
  const int n0 = blockIdx.x * 64, c0 = blockIdx.y * 64, b = blockIdx.z;
  __shared__ __bf16 l[64][72];  // [n][c]
  const int tid = threadIdx.x;
  const int cl = tid >> 2, seg = (tid & 3) * 16;
  const float ca = coefA[b * NC + c0 + cl], cb = coefB[b * NC + c0 + cl];
  const float4* src = (const float4*)(x + (size_t)(b * NC + c0 + cl) * NSPA + n0 + seg);
#pragma unroll
  for (int i = 0; i < 4; ++i) {
    float4 v = src[i];
    l[seg + i * 4 + 0][cl] = tob(v.x * ca + cb);
    l[seg + i * 4 + 1][cl] = tob(v.y * ca + cb);
    l[seg + i * 4 + 2][cl] = tob(v.z * ca + cb);
    l[seg + i * 4 + 3][cl] = tob(v.w * ca + cb);
  }
  __syncthreads();
#pragma unroll
  for (int i = 0; i < 2; ++i) {
    const int chunk = tid + i * 256;
    const int row = chunk >> 3, s = chunk & 7;
    *(bf16x8*)(xnT + (size_t)(b * NSPA + n0 + row) * NC + c0 + s * 8) =
        *(const bf16x8*)&l[row][s * 8];
  }
}

// ---------------------------------------------------------------------------
// GEMM core v3: 128x128 tile, BK=64, 256 thr (4 waves 2x2, 64x64/wave, 4x4
// frags). 2-phase LDS double-buffer (T3-min) + XOR-swizzled tiles (T2, done
// rule-#21 style: linear gload_lds dest + permuted GLOBAL source + XOR read)
// + setprio around MFMA cluster (T5).
// Swizzle: 16B slot s of row r holds global chunk s^(r&7); read col-index
// XORs (r&7)<<3. After swizzle a wave's 64 b128 lanes cover all 8 slots
// (8 lanes/slot) = conflict-floor, vs 16-way linear.
// ---------------------------------------------------------------------------
__device__ __forceinline__ void stage_pair(const __bf16* __restrict__ A, int lda,
                                           const __bf16* __restrict__ B, int ldb,
                                           int k0, __bf16* lAf, __bf16* lBf) {
  const int tid = threadIdx.x;
#pragma unroll
  for (int i = 0; i < 4; ++i) {
    const int idx = tid + i * 256;
    const int srow = idx >> 3;
    const int ss = ((idx & 7) ^ (srow & 7)) * 8;  // inverse-swizzled source chunk
    GLDS16(A + (size_t)srow * lda + k0 + ss, lAf + idx * 8);
    GLDS16(B + (size_t)srow * ldb + k0 + ss, lBf + idx * 8);
  }
}

__device__ __forceinline__ void gemm_core_db(const __bf16* __restrict__ A, int lda,
                                             const __bf16* __restrict__ B, int ldb,
                                             int K, __bf16 (*lA)[128][64],
                                             __bf16 (*lB)[128][64], f32x4 acc[4][4]) {
  const int tid = threadIdx.x;
  const int lane = tid & 63, wave = tid >> 6;
  const int wm = (wave >> 1) * 64, wn = (wave & 1) * 64;
  const int fr = lane & 15, fg = (lane >> 4) * 8;
  const int nt = K >> 6;

  stage_pair(A, lda, B, ldb, 0, &lA[0][0][0], &lB[0][0][0]);
  asm volatile("s_waitcnt vmcnt(0)" ::: "memory");
  __syncthreads();
  int cur = 0;
  for (int t = 0; t < nt; ++t) {
    if (t + 1 < nt)
      stage_pair(A, lda, B, ldb, (t + 1) * 64, &lA[cur ^ 1][0][0], &lB[cur ^ 1][0][0]);
    __builtin_amdgcn_s_setprio(1);
#pragma unroll
    for (int ks = 0; ks < 2; ++ks) {
      bf16x8 af[4], bfr[4];
#pragma unroll
      for (int mi = 0; mi < 4; ++mi) {
        const int r = wm + mi * 16 + fr;
        af[mi] = *(const bf16x8*)&lA[cur][r][(ks * 32 + fg) ^ ((r & 7) << 3)];
      }
#pragma unroll
      for (int ni = 0; ni < 4; ++ni) {
        const int r = wn + ni * 16 + fr;
        bfr[ni] = *(const bf16x8*)&lB[cur][r][(ks * 32 + fg) ^ ((r & 7) << 3)];
      }
#pragma unroll
      for (int mi = 0; mi < 4; ++mi)
#pragma unroll
        for (int ni = 0; ni < 4; ++ni)
          acc[mi][ni] = __builtin_amdgcn_mfma_f32_16x16x32_bf16(af[mi], bfr[ni], acc[mi][ni], 0, 0, 0);
    }
    __builtin_amdgcn_s_setprio(0);
    if (t + 1 < nt) {
      asm volatile("s_waitcnt vmcnt(0)" ::: "memory");
      __syncthreads();
      cur ^= 1;
    }
  }
}

// ---------------------------------------------------------------------------
// K3: QKV GEMM. C[o][n] = Wqkv[o][c] x xnT[n][c]^T (+bias).
//   o <  1024 (q,k): transposed store -> qk[b][n][o]   (bf16x4, contiguous)
//   o >= 1024 (v)  : natural store    -> v[b][o-1024][n]
// ---------------------------------------------------------------------------
__global__ __launch_bounds__(256, 2) void qkv_gemm_kernel(
    const __bf16* __restrict__ wqb, const __bf16* __restrict__ xnT,
    const float* __restrict__ bqkv, __bf16* __restrict__ qk, __bf16* __restrict__ v) {
  const int n0 = blockIdx.x * 128, m0 = blockIdx.y * 128, b = blockIdx.z;
  __shared__ __bf16 lA[2][128][64], lB[2][128][64];
  f32x4 acc[4][4] = {};
  gemm_core_db(wqb + (size_t)m0 * NC, NC, xnT + ((size_t)b * NSPA + n0) * NC, NC, NC, lA, lB, acc);

  const int lane = threadIdx.x & 63, wave = threadIdx.x >> 6;
  const int wm = (wave >> 1) * 64, wn = (wave & 1) * 64;
  const int fr = lane & 15, fq4 = (lane >> 4) * 4;
  if (m0 < NSPA) {
#pragma unroll
    for (int mi = 0; mi < 4; ++mi) {
      const int m = m0 + wm + mi * 16 + fq4;
      const float4 bias = *(const float4*)(bqkv + m);
#pragma unroll
      for (int ni = 0; ni < 4; ++ni) {
        const int n = n0 + wn + ni * 16 + fr;
        bf16x4 w;
        w[0] = tob(acc[mi][ni][0] + bias.x);
        w[1] = tob(acc[mi][ni][1] + bias.y);
        w[2] = tob(acc[mi][ni][2] + bias.z);
        w[3] = tob(acc[mi][ni][3] + bias.w);
        *(bf16x4*)(qk + ((size_t)b * NSPA + n) * NSPA + m) = w;
      }
    }
  } else {
#pragma unroll
    for (int mi = 0; mi < 4; ++mi) {
      const int m = m0 + wm + mi * 16 + fq4;        // o index (>=1024)
      const float4 bias = *(const float4*)(bqkv + m);
      const int vr = m - NSPA;
#pragma unroll
      for (int ni = 0; ni < 4; ++ni) {
        const int n = n0 + wn + ni * 16 + fr;
        v[((size_t)b * NC + vr + 0) * NSPA + n] = tob(acc[mi][ni][0] + bias.x);
        v[((size_t)b * NC + vr + 1) * NSPA + n] = tob(acc[mi][ni][1] + bias.y);
        v[((size_t)b * NC + vr + 2) * NSPA + n] = tob(acc[mi][ni][2] + bias.z);
        v[((size_t)b * NC + vr + 3) * NSPA + n] = tob(acc[mi][ni][3] + bias.w);
      }
    }
  }
}

// ---------------------------------------------------------------------------
// K4: scores (swapped). C[j][i] = k[j][d] . q[i][d]; store P[b][i][j] * SCL.
// ---------------------------------------------------------------------------
__global__ __launch_bounds__(256, 2) void scores_kernel(const __bf16* __restrict__ qk,
                                                        __bf16* __restrict__ P) {
  const int i0 = blockIdx.x * 128, j0 = blockIdx.y * 128, b = blockIdx.z;
  const __bf16* base = qk + (size_t)b * NSPA * NSPA;
  __shared__ __bf16 lA[2][128][64], lB[2][128][64];
  f32x4 acc[4][4] = {};
  gemm_core_db(base + (size_t)j0 * NSPA + NC, NSPA, base + (size_t)i0 * NSPA, NSPA, NC, lA, lB, acc);

  const int lane = threadIdx.x & 63, wave = threadIdx.x >> 6;
  const int wm = (wave >> 1) * 64, wn = (wave & 1) * 64;
  const int fr = lane & 15, fq4 = (lane >> 4) * 4;
#pragma unroll
  for (int mi = 0; mi < 4; ++mi) {
    const int j = j0 + wm + mi * 16 + fq4;
#pragma unroll
    for (int ni = 0; ni < 4; ++ni) {
      const int i = i0 + wn + ni * 16 + fr;
      bf16x4 w;
      w[0] = tob(acc[mi][ni][0] * SCL);
      w[1] = tob(acc[mi][ni][1] * SCL);
      w[2] = tob(acc[mi][ni][2] * SCL);
      w[3] = tob(acc[mi][ni][3] * SCL);
      *(bf16x4*)(P + ((size_t)b * NSPA + i) * NSPA + j) = w;
    }
  }
}

// ---------------------------------------------------------------------------
// K5: in-place row softmax on bf16 P
// ---------------------------------------------------------------------------
__global__ void softmax_kernel(__bf16* __restrict__ P) {
  const int row = blockIdx.x;
  __bf16* p = P + (size_t)row * NSPA;
  const int tid = threadIdx.x;
  bf16x4 v = *((const bf16x4*)p + tid);
  float f0 = (float)v[0], f1 = (float)v[1], f2 = (float)v[2], f3 = (float)v[3];
  float m = fmaxf(fmaxf(f0, f1), fmaxf(f2, f3));
#pragma unroll
  for (int off = 32; off; off >>= 1) m = fmaxf(m, __shfl_xor(m, off));
  __shared__ float red[4];
  const int wave = tid >> 6, lane = tid & 63;
  if (lane == 0) red[wave] = m;
  __syncthreads();
  m = fmaxf(fmaxf(red[0], red[1]), fmaxf(red[2], red[3]));
  float e0 = __expf(f0 - m), e1 = __expf(f1 - m), e2 = __expf(f2 - m), e3 = __expf(f3 - m);
  float s = (e0 + e1) + (e2 + e3);
#pragma unroll
  for (int off = 32; off; off >>= 1) s += __shfl_xor(s, off);
  __syncthreads();
  if (lane == 0) red[wave] = s;
  __syncthreads();
  s = (red[0] + red[1]) + (red[2] + red[3]);
  const float inv = 1.f / s;
  v[0] = tob(e0 * inv); v[1] = tob(e1 * inv); v[2] = tob(e2 * inv); v[3] = tob(e3 * inv);
  *((bf16x4*)p + tid) = v;
}

// ---------------------------------------------------------------------------
// K6: PV. C[d][i] = v[d][j] . P[i][j]; transposed store -> attn[b][i][d].
// ---------------------------------------------------------------------------
__global__ __launch_bounds__(256, 2) void pv_kernel(const __bf16* __restrict__ v,
                                                    const __bf16* __restrict__ P,
                                                    __bf16* __restrict__ attn) {
  const int i0 = blockIdx.x * 128, d0 = blockIdx.y * 128, b = blockIdx.z;
  __shared__ __bf16 lA[2][128][64], lB[2][128][64];
  f32x4 acc[4][4] = {};
  gemm_core_db(v + ((size_t)b * NC + d0) * NSPA, NSPA,
               P + ((size_t)b * NSPA + i0) * NSPA, NSPA, NSPA, lA, lB, acc);

  const int lane = threadIdx.x & 63, wave = threadIdx.x >> 6;
  const int wm = (wave >> 1) * 64, wn = (wave & 1) * 64;
  const int fr = lane & 15, fq4 = (lane >> 4) * 4;
#pragma unroll
  for (int mi = 0; mi < 4; ++mi) {
    const int d = d0 + wm + mi * 16 + fq4;
#pragma unroll
    for (int ni = 0; ni < 4; ++ni) {
      const int i = i0 + wn + ni * 16 + fr;
      bf16x4 w;
      w[0] = tob(acc[mi][ni][0]);
      w[1] = tob(acc[mi][ni][1]);
      w[2] = tob(acc[mi][ni][2]);
      w[3] = tob(acc[mi][ni][3]);
      *(bf16x4*)(attn + ((size_t)b * NSPA + i) * NC + d) = w;
    }
  }
}

// ---------------------------------------------------------------------------
// K7: out-proj. C[o][n] = Wout[o][c] . attn[n][c] + bias + x, fp32 natural.
// ---------------------------------------------------------------------------
__global__ __launch_bounds__(256, 2) void out_gemm_kernel(
    const __bf16* __restrict__ wob, const __bf16* __restrict__ attn,
    const float* __restrict__ bout, const float* __restrict__ x,
    float* __restrict__ out) {
  const int n0 = blockIdx.x * 128, m0 = blockIdx.y * 128, b = blockIdx.z;
  __shared__ __bf16 lA[2][128][64], lB[2][128][64];
  f32x4 acc[4][4] = {};
  gemm_core_db(wob + (size_t)m0 * NC, NC, attn + ((size_t)b * NSPA + n0) * NC, NC, NC, lA, lB, acc);

  const int lane = threadIdx.x & 63, wave = threadIdx.x >> 6;
  const int wm = (wave >> 1) * 64, wn = (wave & 1) * 64;
  const int fr = lane & 15, fq4 = (lane >> 4) * 4;
#pragma unroll
  for (int mi = 0; mi < 4; ++mi) {
    const int m = m0 + wm + mi * 16 + fq4;
    const float4 bias = *(const float4*)(bout + m);
#pragma unroll
    for (int ni = 0; ni < 4; ++ni) {
      const int n = n0 + wn + ni * 16 + fr;
      const size_t i0x = ((size_t)b * NC + m) * NSPA + n;
      out[i0x + 0 * NSPA] = acc[mi][ni][0] + bias.x + x[i0x + 0 * NSPA];
      out[i0x + 1 * NSPA] = acc[mi][ni][1] + bias.y + x[i0x + 1 * NSPA];
      out[i0x + 2 * NSPA] = acc[mi][ni][2] + bias.z + x[i0x + 2 * NSPA];
      out[i0x + 3 * NSPA] = acc[mi][ni][3] + bias.w + x[i0x + 3 * NSPA];
    }
  }
}

// ---------------------------------------------------------------------------
// Workspace (~66 MB):
//   coefA/coefB: 2x32 KB | xnT/attn: 16 MB | wqb 1.5 MB | wob 0.5 MB
//   v: 16 MB | P: 32 MB.  qk (32 MB) lives in d_out (dead until out_gemm).
// ---------------------------------------------------------------------------
extern "C" void kernel_launch(void* const* d_in, const int* in_sizes, int n_in,
                              void* d_out, int out_size, void* d_ws, size_t ws_size,
                              hipStream_t stream) {
  const float* x        = (const float*)d_in[0];
  const float* gn_scale = (const float*)d_in[3];
  const float* gn_bias  = (const float*)d_in[4];
  const float* w_qkv    = (const float*)d_in[5];
  const float* b_qkv    = (const float*)d_in[6];
  const float* w_out    = (const float*)d_in[7];
  const float* b_out    = (const float*)d_in[8];
  float* out = (float*)d_out;

  char* ws = (char*)d_ws;
  float*  coefA = (float*)ws;                                   // 32 KB
  float*  coefB = coefA + NB * NC;                              // 32 KB
  __bf16* xnT   = (__bf16*)(ws + (64 << 10));                   // 16 MB (also attn)
  __bf16* attn  = xnT;
  __bf16* wqb   = xnT + (size_t)NB * NSPA * NC;                 // 1.5 MB
  __bf16* wob   = wqb + (size_t)NO3 * NC;                       // 0.5 MB
  __bf16* vbuf  = wob + (size_t)NC * NC;                        // 16 MB
  __bf16* P     = vbuf + (size_t)NB * NC * NSPA;                // 32 MB
  __bf16* qk    = (__bf16*)d_out;                               // 32 MB scratch in out

  gn_stats_kernel<<<dim3(NB * 32), 256, 0, stream>>>(x, gn_scale, gn_bias, coefA, coefB);
  pack_w_kernel<<<dim3((NO3 * NC + NC * NC) / 4 / 256), 256, 0, stream>>>(w_qkv, w_out, wqb, wob);
  pack_x_kernel<<<dim3(NSPA / 64, NC / 64, NB), 256, 0, stream>>>(x, coefA, coefB, xnT);
  qkv_gemm_kernel<<<dim3(8, 12, NB), 256, 0, stream>>>(wqb, xnT, b_qkv, qk, vbuf);
  scores_kernel<<<dim3(8, 8, NB), 256, 0, stream>>>(qk, P);
  softmax_kernel<<<dim3(NB * NSPA), 256, 0, stream>>>(P);
  pv_kernel<<<dim3(8, 4, NB), 256, 0, stream>>>(vbuf, P, attn);
  out_gemm_kernel<<<dim3(8, 4, NB), 256, 0, stream>>>(wob, attn, b_out, x, out);
}